// Round 4
// baseline (3857.750 us; speedup 1.0000x reference)
//
#include <hip/hip_runtime.h>

// Problem constants (E,B,C,H,W) = (3,8,10,512,512), HIDDEN=256
#define HWQ   262144      // H*W
#define CHW   2621440     // C*H*W
#define BCHW  20971520    // B*C*H*W
#define NTOT  2097152     // B*H*W
#define TAU   0.05f       // doubt margin: ~40 sigma of bf16-path logit error

typedef float v2f  __attribute__((ext_vector_type(2)));
typedef float f4   __attribute__((ext_vector_type(4)));
typedef short short8 __attribute__((ext_vector_type(8)));
typedef unsigned int u4 __attribute__((ext_vector_type(4)));

__device__ __forceinline__ short f2bf(float f) {   // RNE, matches hw cvt
    unsigned u = __float_as_uint(f);
    u += 0x7FFF + ((u >> 16) & 1);
    return (short)(u >> 16);
}

// ---------------- K0: zero the queue counter ----------------
__global__ void k0_zero(int* qcount) { qcount[0] = 0; }

// ---------------- K1: bf16 MFMA logits + sel + doubt queue ----------------
// Block = 256 thr = 4 waves; block handles 256 consecutive positions
// (one wave: 64 positions = 4 M-tiles of 16). Never straddles a batch b.
__global__ __launch_bounds__(256)
void k1_mfma_sel(const float* __restrict__ inputs,
                 const float* __restrict__ w1,
                 const float* __restrict__ b1,
                 const float* __restrict__ w2,
                 const float* __restrict__ b2,
                 float* __restrict__ out1,
                 int* __restrict__ qcount,
                 int* __restrict__ queue) {
    __shared__ u4 ldsB[16 * 64];     // w1 bf16 B-fragments, 16 KB
    __shared__ f4 ldsW2[256];        // {w2[n][0..2], b1[n]}, 4 KB

    const int tid = threadIdx.x;
    // ---- stage B-fragments: B[k=(ls>>4)*8+j][n=t*16+(ls&15)] ----
    {
        const int ls = tid & 63;
        #pragma unroll
        for (int pass = 0; pass < 4; ++pass) {
            const int t = pass * 4 + (tid >> 6);
            const int n = t * 16 + (ls & 15);
            const int kb = (ls >> 4) * 8;
            unsigned up[4];
            #pragma unroll
            for (int pj = 0; pj < 4; ++pj) {
                int k0 = kb + 2 * pj, k1 = kb + 2 * pj + 1;
                unsigned lo = (k0 < 30) ? (unsigned short)f2bf(w1[k0 * 256 + n]) : 0u;
                unsigned hi = (k1 < 30) ? (unsigned short)f2bf(w1[k1 * 256 + n]) : 0u;
                up[pj] = lo | (hi << 16);
            }
            u4 v; v.x = up[0]; v.y = up[1]; v.z = up[2]; v.w = up[3];
            ldsB[t * 64 + ls] = v;
        }
        f4 wv; wv.x = w2[tid * 3 + 0]; wv.y = w2[tid * 3 + 1];
        wv.z = w2[tid * 3 + 2]; wv.w = b1[tid];
        ldsW2[tid] = wv;
    }
    __syncthreads();

    const int lane = tid & 63;
    const int wv   = tid >> 6;
    const int ln   = lane & 15;
    const int quad = lane >> 4;
    const int blockbase = blockIdx.x * 256;
    const int b   = blockbase >> 18;                  // uniform per block
    const int hwb = (blockbase & (HWQ - 1)) + wv * 64;
    const float* __restrict__ pb = inputs + b * CHW;

    // per-lane k-plane offsets for its A quad
    int koff[8]; bool kval[8];
    {
        const int kb = quad * 8;
        #pragma unroll
        for (int j = 0; j < 8; ++j) {
            int k = kb + j;
            kval[j] = (k < 30);
            int e = (k * 205) >> 11;                  // k/10 for k<32
            int c = k - 10 * e;
            koff[j] = kval[j] ? (e * BCHW + c * HWQ) : 0;
        }
    }

    // ---- load & quantize A-fragments: A[m=ln][k=quad*8+j] ----
    short8 afrag[4];
    #pragma unroll
    for (int mt = 0; mt < 4; ++mt) {
        const int hw = hwb + mt * 16 + ln;
        float xv[8];
        #pragma unroll
        for (int j = 0; j < 8; ++j) xv[j] = pb[koff[j] + hw];
        short8 a;
        #pragma unroll
        for (int j = 0; j < 8; ++j) a[j] = kval[j] ? f2bf(xv[j]) : (short)0;
        afrag[mt] = a;
    }

    // ---- MFMA over 16 N-tiles, fold layer 2 immediately ----
    float acc[4][4][3];
    #pragma unroll
    for (int mt = 0; mt < 4; ++mt)
        #pragma unroll
        for (int rg = 0; rg < 4; ++rg)
            acc[mt][rg][0] = acc[mt][rg][1] = acc[mt][rg][2] = 0.f;

    #pragma unroll
    for (int t = 0; t < 16; ++t) {
        u4 braw = ldsB[t * 64 + lane];
        short8 bfrag = __builtin_bit_cast(short8, braw);
        f4 wb = ldsW2[t * 16 + ln];   // col n = t*16+ln for this lane
        #pragma unroll
        for (int mt = 0; mt < 4; ++mt) {
            f4 c0 = {0.f, 0.f, 0.f, 0.f};
            c0 = __builtin_amdgcn_mfma_f32_16x16x32_bf16(afrag[mt], bfrag, c0, 0, 0, 0);
            #pragma unroll
            for (int rg = 0; rg < 4; ++rg) {
                float h = fmaxf(c0[rg] + wb.w, 0.f);   // + b1[n], relu
                acc[mt][rg][0] = fmaf(h, wb.x, acc[mt][rg][0]);
                acc[mt][rg][1] = fmaf(h, wb.y, acc[mt][rg][1]);
                acc[mt][rg][2] = fmaf(h, wb.z, acc[mt][rg][2]);
            }
        }
    }

    // ---- reduce partial logits across the 16 col-lanes ----
    #pragma unroll
    for (int d = 1; d < 16; d <<= 1)
        #pragma unroll
        for (int mt = 0; mt < 4; ++mt)
            #pragma unroll
            for (int rg = 0; rg < 4; ++rg)
                #pragma unroll
                for (int e = 0; e < 3; ++e)
                    acc[mt][rg][e] += __shfl_xor(acc[mt][rg][e], d, 64);

    // ---- argmax + margin; writer lane per row: ln == rg ----
    const float b20 = b2[0], b21 = b2[1], b22 = b2[2];
    const int wavebase = blockbase + wv * 64;
    #pragma unroll
    for (int rg = 0; rg < 4; ++rg) {
        if (ln == rg) {
            #pragma unroll
            for (int mt = 0; mt < 4; ++mt) {
                float l0 = acc[mt][rg][0] + b20;
                float l1 = acc[mt][rg][1] + b21;
                float l2 = acc[mt][rg][2] + b22;
                int sel = 0; float best = l0, second;
                if (l1 > best) { second = best; best = l1; sel = 1; }
                else           { second = l1; }
                if (l2 > best) { second = best; best = l2; sel = 2; }
                else if (l2 > second) { second = l2; }
                const int p = wavebase + mt * 16 + quad * 4 + rg;
                out1[p] = (float)sel;
                if (best - second < TAU) {
                    int idx = atomicAdd(qcount, 1);
                    queue[idx] = p;
                }
            }
        }
    }
}

// ---------------- K2: exact fp32 repair (round-2 op order, verbatim) -------
__global__ __launch_bounds__(256)
void k2_repair(const float* __restrict__ inputs,
               const float* __restrict__ w1,
               const float* __restrict__ b1,
               const float* __restrict__ w2,
               const float* __restrict__ b2,
               float* __restrict__ out1,
               const int* __restrict__ qcount,
               const int* __restrict__ queue) {
    __shared__ v2f smem[256 * 18];
    {   // identical staging to round-2 kernel
        const int j = threadIdx.x;
        v2f* row = &smem[j * 18];
        #pragma unroll
        for (int kk = 0; kk < 15; ++kk) {
            v2f t;
            t.x = w1[(2 * kk    ) * 256 + j];
            t.y = w1[(2 * kk + 1) * 256 + j];
            row[kk] = t;
        }
        v2f t15; t15.x = b1[j];         t15.y = w2[j * 3 + 0]; row[15] = t15;
        v2f t16; t16.x = w2[j * 3 + 1]; t16.y = w2[j * 3 + 2]; row[16] = t16;
    }
    __syncthreads();

    const int count  = qcount[0];
    const int stride = gridDim.x * 256;
    const float b20 = b2[0], b21 = b2[1], b22 = b2[2];

    for (int i = blockIdx.x * 256 + threadIdx.x; i < count; i += stride) {
        const int p = queue[i];
        const int q = p >> 18;
        const int r = p & (HWQ - 1);
        const float* __restrict__ px = inputs + (long)q * CHW + r;
        v2f x2[15];
        #pragma unroll
        for (int k = 0; k < 30; ++k) {
            const int e = k / 10, c = k % 10;
            float v = px[(long)e * BCHW + (long)c * HWQ];
            if (k & 1) x2[k / 2].y = v; else x2[k / 2].x = v;
        }
        float l0 = b20, l1 = b21, l2 = b22;
        #pragma unroll 2
        for (int j = 0; j < 256; ++j) {
            const v2f* __restrict__ wrow = &smem[j * 18];
            const v2f bw  = wrow[15];
            const v2f w12 = wrow[16];
            v2f h2; h2.x = bw.x; h2.y = 0.f;
            #pragma unroll
            for (int kk = 0; kk < 15; ++kk)
                h2 = __builtin_elementwise_fma(x2[kk], wrow[kk], h2);
            const float hm = fmaxf(h2.x + h2.y, 0.f);
            l0 = fmaf(hm, bw.y,  l0);
            l1 = fmaf(hm, w12.x, l1);
            l2 = fmaf(hm, w12.y, l2);
        }
        int sel = 0; float best = l0;
        if (l1 > best) { best = l1; sel = 1; }
        if (l2 > best) { sel = 2; }
        out1[p] = (float)sel;
    }
}

// ---------------- K3: gather-copy the winning expert's 10 planes ----------
__global__ __launch_bounds__(256)
void k3_copy(const float* __restrict__ inputs,
             const float* __restrict__ out1,
             float* __restrict__ out0) {
    const int n  = blockIdx.x * 256 + threadIdx.x;
    const int sel = (int)out1[n];
    const int b  = n >> 18;
    const int hw = n & (HWQ - 1);
    const float* __restrict__ src = inputs + sel * BCHW + b * CHW + hw;
    float* __restrict__ dst = out0 + b * CHW + hw;
    #pragma unroll
    for (int c = 0; c < 10; ++c)
        dst[c * HWQ] = src[c * HWQ];
}

// ---------------- fallback: round-2 monolithic fp32 kernel ----------------
#define NPT   4
#define NTHREAD (NTOT / NPT)
__global__ __launch_bounds__(256)
void mlp_select_fused(const float* __restrict__ inputs,
                      const float* __restrict__ w1,
                      const float* __restrict__ b1,
                      const float* __restrict__ w2,
                      const float* __restrict__ b2,
                      float* __restrict__ out0,
                      float* __restrict__ out1) {
    __shared__ v2f smem[256 * 18];
    {
        const int j = threadIdx.x;
        v2f* row = &smem[j * 18];
        #pragma unroll
        for (int kk = 0; kk < 15; ++kk) {
            v2f t;
            t.x = w1[(2 * kk    ) * 256 + j];
            t.y = w1[(2 * kk + 1) * 256 + j];
            row[kk] = t;
        }
        v2f t15; t15.x = b1[j];         t15.y = w2[j * 3 + 0]; row[15] = t15;
        v2f t16; t16.x = w2[j * 3 + 1]; t16.y = w2[j * 3 + 2]; row[16] = t16;
        v2f t17; t17.x = 0.f;           t17.y = 0.f;           row[17] = t17;
    }
    __syncthreads();
    const int tid = blockIdx.x * 256 + threadIdx.x;
    v2f x2[NPT][15];
    int q[NPT], r[NPT];
    #pragma unroll
    for (int m = 0; m < NPT; ++m) {
        int n = tid + m * NTHREAD;
        q[m] = n >> 18; r[m] = n & (HWQ - 1);
        const float* __restrict__ p = inputs + (long)q[m] * CHW + r[m];
        #pragma unroll
        for (int k = 0; k < 30; ++k) {
            const int e = k / 10, c = k % 10;
            float v = p[(long)e * BCHW + (long)c * HWQ];
            if (k & 1) x2[m][k / 2].y = v; else x2[m][k / 2].x = v;
        }
    }
    const float b20 = b2[0], b21 = b2[1], b22 = b2[2];
    float l[NPT][3];
    #pragma unroll
    for (int m = 0; m < NPT; ++m) { l[m][0] = b20; l[m][1] = b21; l[m][2] = b22; }
    #pragma unroll 2
    for (int j = 0; j < 256; ++j) {
        const v2f* __restrict__ wrow = &smem[j * 18];
        const v2f bw  = wrow[15];
        const v2f w12 = wrow[16];
        v2f h2[NPT];
        #pragma unroll
        for (int m = 0; m < NPT; ++m) { v2f t; t.x = bw.x; t.y = 0.f; h2[m] = t; }
        #pragma unroll
        for (int kk = 0; kk < 15; ++kk) {
            const v2f wk = wrow[kk];
            #pragma unroll
            for (int m = 0; m < NPT; ++m)
                h2[m] = __builtin_elementwise_fma(x2[m][kk], wk, h2[m]);
        }
        #pragma unroll
        for (int m = 0; m < NPT; ++m) {
            const float hm = fmaxf(h2[m].x + h2[m].y, 0.f);
            l[m][0] = fmaf(hm, bw.y,  l[m][0]);
            l[m][1] = fmaf(hm, w12.x, l[m][1]);
            l[m][2] = fmaf(hm, w12.y, l[m][2]);
        }
    }
    #pragma unroll
    for (int m = 0; m < NPT; ++m) {
        int sel = 0; float best = l[m][0];
        if (l[m][1] > best) { best = l[m][1]; sel = 1; }
        if (l[m][2] > best) { sel = 2; }
        const bool s1 = (sel == 1), s2 = (sel == 2);
        float* __restrict__ o = out0 + (long)q[m] * CHW + r[m];
        #pragma unroll
        for (int c = 0; c < 10; ++c) {
            const int k0 = c, k1 = 10 + c, k2 = 20 + c;
            const float v0 = (k0 & 1) ? x2[m][k0 / 2].y : x2[m][k0 / 2].x;
            const float v1 = (k1 & 1) ? x2[m][k1 / 2].y : x2[m][k1 / 2].x;
            const float v2 = (k2 & 1) ? x2[m][k2 / 2].y : x2[m][k2 / 2].x;
            o[(long)c * HWQ] = s2 ? v2 : (s1 ? v1 : v0);
        }
        out1[tid + m * NTHREAD] = (float)sel;
    }
}

extern "C" void kernel_launch(void* const* d_in, const int* in_sizes, int n_in,
                              void* d_out, int out_size, void* d_ws, size_t ws_size,
                              hipStream_t stream) {
    const float* inputs = (const float*)d_in[0];
    const float* w1     = (const float*)d_in[1];
    const float* b1     = (const float*)d_in[2];
    const float* w2     = (const float*)d_in[3];
    const float* b2     = (const float*)d_in[4];
    float* out0 = (float*)d_out;
    float* out1 = out0 + BCHW;

    const size_t ws_need = (size_t)(NTOT + 256) * sizeof(int);
    if (ws_size >= ws_need) {
        int* qcount = (int*)d_ws;
        int* queue  = (int*)d_ws + 256;
        k0_zero<<<1, 1, 0, stream>>>(qcount);
        k1_mfma_sel<<<NTOT / 256, 256, 0, stream>>>(inputs, w1, b1, w2, b2,
                                                    out1, qcount, queue);
        k2_repair<<<256, 256, 0, stream>>>(inputs, w1, b1, w2, b2,
                                           out1, qcount, queue);
        k3_copy<<<NTOT / 256, 256, 0, stream>>>(inputs, out1, out0);
    } else {
        mlp_select_fused<<<NTOT / (256 * NPT), 256, 0, stream>>>(
            inputs, w1, b1, w2, b2, out0, out1);
    }
}